// Round 5
// baseline (124.963 us; speedup 1.0000x reference)
//
#include <hip/hip_runtime.h>
#include <math.h>

constexpr int Bn = 64;
constexpr int Dn = 1024;
constexpr float LOG2E = 1.4426950408889634f;
constexpr float LN2   = 0.6931471805599453f;

__device__ __forceinline__ float exp2_fast(float v) {
#if defined(__has_builtin)
#if __has_builtin(__builtin_amdgcn_exp2f)
  return __builtin_amdgcn_exp2f(v);
#else
  return exp2f(v);
#endif
#else
  return exp2f(v);
#endif
}

// ---------------------------------------------------------------------------
// K0: fused bucket-sort + analytic Bsum + pairs.  One block per b.
// Buckets (64) are disjoint x-intervals via monotone logistic map, so for
// element x in bucket q:  Bsum = x*(Nlo-Nhi) + (Shi-Slo) + sum_{k in q}|x-x_k|
// (exact regardless of within-bucket order; cross terms from prefix scans).
// Emits pairs_s[b][pos] = (x*log2e, -Bsum*log2e) in near-sorted order.
// Also zeroes d_out (atomics target for the TAIL layer).
// ---------------------------------------------------------------------------
__global__ __launch_bounds__(256) void k0_sort_bsum(
    const float* __restrict__ x, float2* __restrict__ pairs_s,
    float* __restrict__ out) {
  int b = blockIdx.x;
  int tid = threadIdx.x;
  __shared__ float xs_[Dn];
  __shared__ int   bkt_[Dn];
  __shared__ int   cnt[64], base_[64], off_[64];
  __shared__ float Ssum[64], cN[64], cS[64];
  if (tid < 64) { cnt[tid] = 0; off_[tid] = 0; Ssum[tid] = 0.f; }
  __syncthreads();
  float4 v4 = *(const float4*)(x + b * Dn + tid * 4);
  float xv[4] = {v4.x, v4.y, v4.z, v4.w};
  int bk[4];
#pragma unroll
  for (int u = 0; u < 4; ++u) {
    float z = exp2_fast(-2.455532f * xv[u]);   // e^{-1.702 x} (monotone)
    float p = 1.f / (1.f + z);                 // logistic, monotone in x
    int t = (int)(p * 64.f);
    bk[u] = t < 0 ? 0 : (t > 63 ? 63 : t);
    atomicAdd(&cnt[bk[u]], 1);
    atomicAdd(&Ssum[bk[u]], xv[u]);
  }
  __syncthreads();
  if (tid < 64) {                              // wave 0: dual prefix scan
    int c = cnt[tid]; int si = c;
    float fs = Ssum[tid]; float ss = fs;
#pragma unroll
    for (int d = 1; d < 64; d <<= 1) {
      int oi = __shfl_up(si, d, 64);
      float os = __shfl_up(ss, d, 64);
      if (tid >= d) { si += oi; ss += os; }
    }
    base_[tid] = si - c;                       // Nlo (exclusive)
    float Stot = __shfl(ss, 63, 64);
    float Slo = ss - fs;                       // exclusive sum prefix
    cN[tid] = (float)(2 * (si - c) + c - Dn);  // Nlo - Nhi
    cS[tid] = Stot - 2.f * Slo - fs;           // Shi - Slo
  }
  __syncthreads();
#pragma unroll
  for (int u = 0; u < 4; ++u) {
    int pos = base_[bk[u]] + atomicAdd(&off_[bk[u]], 1);
    xs_[pos] = xv[u];
    bkt_[pos] = bk[u];
  }
  __syncthreads();
#pragma unroll
  for (int u = 0; u < 4; ++u) {
    int p = tid * 4 + u;
    float xp = xs_[p];
    int q = bkt_[p];
    int lo = base_[q], hi = lo + cnt[q];
    float local = 0.f;
    for (int k = lo; k < hi; ++k) local += fabsf(xp - xs_[k]);
    float Bs = fmaf(xp, cN[q], cS[q]) + local;
    pairs_s[b * Dn + p] = make_float2(xp * LOG2E, -Bs * LOG2E);
  }
  if (b == 0 && tid < 128) out[tid] = 0.f;
}

// ---------------------------------------------------------------------------
// K2: xs[b,i] = sum_j softmax_j(sc_i*x_j - Bsum_j) * x_j  (exp2 domain).
// Lane = row; waves own interleaved groups-of-8 of the near-sorted positions.
// Pass1: exact max (fma+fma+max3, 1.5 inst/elem) + per-group maxima in regs.
// Pass2: vote-skip groups with gm <= mAll-32 (dropped mass <= 1024*2^-32).
// grid = 64*16 = 1024 blocks of 256.
// ---------------------------------------------------------------------------
__global__ __launch_bounds__(256, 4) void k2_softsort(
    const float2* __restrict__ pairs_s, float* __restrict__ xs_out) {
  __shared__ float redM[4][64], redE[4][64], redD[4][64];
  int b  = blockIdx.x >> 4;
  int rc = blockIdx.x & 15;
  int tid = threadIdx.x;
  int w = tid >> 6, lane = tid & 63;
  int i = rc * 64 + lane;
  float sc = (float)(Dn - 1 - 2 * i);      // exact in fp32
  const float2* ps = pairs_s + b * Dn;

  float gm[32];
  float m = -3.4e38f;
#pragma unroll
  for (int q = 0; q < 32; ++q) {
    int base = (q * 4 + w) * 8;
    float g = -3.4e38f;
#pragma unroll
    for (int u = 0; u < 8; u += 2) {
      float2 v0 = ps[base + u];
      float2 v1 = ps[base + u + 1];
      float t0 = fmaf(sc, v0.x, v0.y);
      float t1 = fmaf(sc, v1.x, v1.y);
      g = fmaxf(g, fmaxf(t0, t1));         // folds to v_max3_f32
    }
    gm[q] = g;
    m = fmaxf(m, g);
  }
  redM[w][lane] = m;
  __syncthreads();
  float mAll = fmaxf(fmaxf(redM[0][lane], redM[1][lane]),
                     fmaxf(redM[2][lane], redM[3][lane]));
  float thresh = mAll - 32.f;

  float se = 0.f, sd = 0.f;
#pragma unroll
  for (int q = 0; q < 32; ++q) {
    if (__any(gm[q] > thresh)) {
      int base = (q * 4 + w) * 8;
#pragma unroll
      for (int u = 0; u < 8; ++u) {
        float2 v = ps[base + u];
        float e = exp2_fast(fmaf(sc, v.x, v.y - mAll));
        se += e;
        sd = fmaf(e, v.x, sd);
      }
    }
  }
  redE[w][lane] = se;
  redD[w][lane] = sd;
  __syncthreads();
  if (tid < 64) {
    float SE = (redE[0][lane] + redE[1][lane]) + (redE[2][lane] + redE[3][lane]);
    float SD = (redD[0][lane] + redD[1][lane]) + (redD[2][lane] + redD[3][lane]);
    xs_out[b * Dn + rc * 64 + lane] = SD / SE * LN2;
  }
}

// ---------------------------------------------------------------------------
// K3/K4: h = leaky(in @ W^T + bias).  Block = 8 batches x 8 cols; thread
// tile = 1 batch x 4 cols x K/16.  grid = 8*128 = 1024 blocks (4/CU,
// 4 waves/SIMD).  Same W traffic as 512-block tiling, 2x latency hiding.
// TAIL fuses layer 3 into atomicAdds on d_out (zeroed by k0).
// ---------------------------------------------------------------------------
template <bool TAIL>
__global__ __launch_bounds__(256) void layer_kernel(
    const float* __restrict__ in, const float* __restrict__ W,
    const float* __restrict__ bias, float* __restrict__ out,
    const float* __restrict__ W3, const float* __restrict__ b3,
    float* __restrict__ out2) {
  __shared__ float s[8][Dn + 4];
  __shared__ float red[8][8][16];          // [bl][nl][kc]
  __shared__ float r2[8][8][2];
  int bc = blockIdx.x >> 7;                // batch chunk 0..7
  int nc = blockIdx.x & 127;               // col chunk 0..127
  int tid = threadIdx.x;
  const float* src = in + bc * 8 * Dn;
#pragma unroll
  for (int u = 0; u < 8; ++u) {
    int idx = (u * 256 + tid) << 2;
    *(float4*)&s[idx >> 10][idx & 1023] = *(const float4*)(src + idx);
  }
  __syncthreads();

  int bl = tid & 7;                        // local batch
  int nq = (tid >> 3) & 1;                 // col quad 0..1
  int kc = tid >> 4;                       // k chunk 0..15 (64 elems)
  int n0 = nc * 8 + nq * 4;
  const float* a  = &s[bl][kc * 64];
  const float* w0 = W + (size_t)(n0 + 0) * Dn + kc * 64;
  const float* w1 = W + (size_t)(n0 + 1) * Dn + kc * 64;
  const float* w2 = W + (size_t)(n0 + 2) * Dn + kc * 64;
  const float* w3 = W + (size_t)(n0 + 3) * Dn + kc * 64;
  float a0 = 0.f, a1 = 0.f, a2 = 0.f, a3 = 0.f;
#pragma unroll 4
  for (int kq = 0; kq < 16; ++kq) {
    float4 av = *(const float4*)(a + kq * 4);
    float4 b0 = *(const float4*)(w0 + kq * 4);
    float4 b1 = *(const float4*)(w1 + kq * 4);
    float4 b2 = *(const float4*)(w2 + kq * 4);
    float4 b3v = *(const float4*)(w3 + kq * 4);
    a0 = fmaf(av.x, b0.x, fmaf(av.y, b0.y, fmaf(av.z, b0.z, fmaf(av.w, b0.w, a0))));
    a1 = fmaf(av.x, b1.x, fmaf(av.y, b1.y, fmaf(av.z, b1.z, fmaf(av.w, b1.w, a1))));
    a2 = fmaf(av.x, b2.x, fmaf(av.y, b2.y, fmaf(av.z, b2.z, fmaf(av.w, b2.w, a2))));
    a3 = fmaf(av.x, b3v.x, fmaf(av.y, b3v.y, fmaf(av.z, b3v.z, fmaf(av.w, b3v.w, a3))));
  }
  red[bl][nq * 4 + 0][kc] = a0;
  red[bl][nq * 4 + 1][kc] = a1;
  red[bl][nq * 4 + 2][kc] = a2;
  red[bl][nq * 4 + 3][kc] = a3;
  __syncthreads();

  if (!TAIL) {
    if (tid < 64) {
      int bl2 = tid >> 3, nl2 = tid & 7;
      int n2 = nc * 8 + nl2;
      float hs = 0.f;
#pragma unroll
      for (int q = 0; q < 16; ++q) hs += red[bl2][nl2][q];
      float h = hs + bias[n2];
      h = h >= 0.f ? h : 0.01f * h;
      out[(bc * 8 + bl2) * Dn + n2] = h;
    }
  } else {
    if (tid < 64) {
      int bl2 = tid >> 3, nl2 = tid & 7;
      int n2 = nc * 8 + nl2;
      float hs = 0.f;
#pragma unroll
      for (int q = 0; q < 16; ++q) hs += red[bl2][nl2][q];
      float h = hs + bias[n2];
      h = h >= 0.f ? h : 0.01f * h;
      r2[bl2][nl2][0] = h * W3[n2];
      r2[bl2][nl2][1] = h * W3[Dn + n2];
    }
    __syncthreads();
    if (tid < 16) {
      int bl2 = tid >> 1, o = tid & 1;
      float t = 0.f;
#pragma unroll
      for (int q = 0; q < 8; ++q) t += r2[bl2][q][o];
      if (nc == 0) t += b3[o];
      atomicAdd(out2 + (bc * 8 + bl2) * 2 + o, t);
    }
  }
}

extern "C" void kernel_launch(void* const* d_in, const int* in_sizes, int n_in,
                              void* d_out, int out_size, void* d_ws, size_t ws_size,
                              hipStream_t stream) {
  const float* x  = (const float*)d_in[0];
  const float* W1 = (const float*)d_in[1];
  const float* b1 = (const float*)d_in[2];
  const float* W2 = (const float*)d_in[3];
  const float* b2 = (const float*)d_in[4];
  const float* W3 = (const float*)d_in[5];
  const float* b3 = (const float*)d_in[6];
  float* out = (float*)d_out;
  float* ws = (float*)d_ws;

  float2* pairs_s = (float2*)ws;                   // 64*1024 float2 = 512 KB
  float*  xs      = (float*)(pairs_s + Bn * Dn);   // 256 KB
  float*  h1      = xs + Bn * Dn;                  // 256 KB

  k0_sort_bsum<<<Bn, 256, 0, stream>>>(x, pairs_s, out);
  k2_softsort<<<Bn * 16, 256, 0, stream>>>(pairs_s, xs);
  layer_kernel<false><<<1024, 256, 0, stream>>>(xs, W1, b1, h1,
                                                nullptr, nullptr, nullptr);
  layer_kernel<true><<<1024, 256, 0, stream>>>(h1, W2, b2, nullptr,
                                               W3, b3, out);
}

// Round 6
// 113.175 us; speedup vs baseline: 1.1042x; 1.1042x over previous
//
#include <hip/hip_runtime.h>
#include <math.h>

constexpr int Bn = 64;
constexpr int Dn = 1024;
constexpr float LOG2E = 1.4426950408889634f;
constexpr float LN2   = 0.6931471805599453f;

__device__ __forceinline__ float exp2_fast(float v) {
#if defined(__has_builtin)
#if __has_builtin(__builtin_amdgcn_exp2f)
  return __builtin_amdgcn_exp2f(v);
#else
  return exp2f(v);
#endif
#else
  return exp2f(v);
#endif
}

// ---------------------------------------------------------------------------
// K0: fused bucket-sort + analytic Bsum + pairs + group descriptors.
// One block (512 thr) per b.  Buckets = disjoint x-intervals (logistic map ~
// normal CDF -> ~uniform 16/bucket).  Bsum = x*(Nlo-Nhi)+(Shi-Slo)+local.
// Descriptors per group of 8 sorted positions: exact (a,c) pairs of the
// group's min-x and max-x elements (T(x) concave -> endpoint bound exact for
// non-straddling groups).  Zeroes d_out.
// ---------------------------------------------------------------------------
__global__ __launch_bounds__(512) void k0_sort_bsum(
    const float* __restrict__ x, float2* __restrict__ pairs_s,
    float4* __restrict__ desc, float* __restrict__ out) {
  int b = blockIdx.x;
  int tid = threadIdx.x;
  __shared__ float xs_[Dn];
  __shared__ float cs_[Dn];
  __shared__ int   bkt_[Dn];
  __shared__ int   cnt[64], base_[64], off_[64];
  __shared__ float Ssum[64], cN[64], cS[64];
  if (tid < 64) { cnt[tid] = 0; off_[tid] = 0; Ssum[tid] = 0.f; }
  __syncthreads();
  float2 v2 = *(const float2*)(x + b * Dn + tid * 2);
  float xv[2] = {v2.x, v2.y};
  int bk[2];
#pragma unroll
  for (int u = 0; u < 2; ++u) {
    float z = exp2_fast(-2.455532f * xv[u]);   // 2^{-1.702 x log2e} monotone
    float p = 1.f / (1.f + z);                 // ~Phi(x): near-uniform buckets
    int t = (int)(p * 64.f);
    bk[u] = t < 0 ? 0 : (t > 63 ? 63 : t);
    atomicAdd(&cnt[bk[u]], 1);
    atomicAdd(&Ssum[bk[u]], xv[u]);
  }
  __syncthreads();
  if (tid < 64) {                              // wave 0: dual prefix scan
    int c = cnt[tid]; int si = c;
    float fs = Ssum[tid]; float ss = fs;
#pragma unroll
    for (int d = 1; d < 64; d <<= 1) {
      int oi = __shfl_up(si, d, 64);
      float os = __shfl_up(ss, d, 64);
      if (tid >= d) { si += oi; ss += os; }
    }
    base_[tid] = si - c;                       // Nlo (exclusive)
    float Stot = __shfl(ss, 63, 64);
    float Slo = ss - fs;                       // exclusive sum prefix
    cN[tid] = (float)(2 * (si - c) + c - Dn);  // Nlo - Nhi
    cS[tid] = Stot - 2.f * Slo - fs;           // Shi - Slo
  }
  __syncthreads();
#pragma unroll
  for (int u = 0; u < 2; ++u) {
    int pos = base_[bk[u]] + atomicAdd(&off_[bk[u]], 1);
    xs_[pos] = xv[u];
    bkt_[pos] = bk[u];
  }
  __syncthreads();
#pragma unroll
  for (int r = 0; r < 2; ++r) {
    int p = r * 512 + tid;
    float xp = xs_[p];
    int q = bkt_[p];
    int lo = base_[q], hi = lo + cnt[q];
    float local = 0.f;
    for (int k = lo; k < hi; ++k) local += fabsf(xp - xs_[k]);
    float Bs = fmaf(xp, cN[q], cS[q]) + local;
    float c = -Bs * LOG2E;
    cs_[p] = c;
    pairs_s[b * Dn + p] = make_float2(xp * LOG2E, c);
  }
  __syncthreads();
  if (tid < 128) {                             // one group of 8 per thread
    int base = tid * 8;
    float xlo = xs_[base], xhi = xlo;
    int ilo = base, ihi = base;
#pragma unroll
    for (int k = 1; k < 8; ++k) {
      float xx = xs_[base + k];
      if (xx < xlo) { xlo = xx; ilo = base + k; }
      if (xx > xhi) { xhi = xx; ihi = base + k; }
    }
    desc[b * 128 + tid] =
        make_float4(xlo * LOG2E, cs_[ilo], xhi * LOG2E, cs_[ihi]);
  }
  if (b == 0 && tid < 128) out[tid] = 0.f;
}

// ---------------------------------------------------------------------------
// K2: xs[b,i] = sum_j softmax_j(sc_i*x_j - Bsum_j) * x_j  (exp2 domain).
// Lane = row; 4 waves own interleaved groups (g = 4q+w).  Group max via the
// concave endpoint bound: 2 fma + max per group (was 12 inst).  Vote-skip
// groups below M-32; process survivors (broadcast global loads).
// grid = 64*16 = 1024 blocks of 256.
// ---------------------------------------------------------------------------
__global__ __launch_bounds__(256, 4) void k2_softsort(
    const float2* __restrict__ pairs_s, const float4* __restrict__ desc,
    float* __restrict__ xs_out) {
  __shared__ float redM[4][64], redE[4][64], redD[4][64];
  int b  = blockIdx.x >> 4;
  int rc = blockIdx.x & 15;
  int tid = threadIdx.x;
  int w = tid >> 6, lane = tid & 63;
  int i = rc * 64 + lane;
  float sc = (float)(Dn - 1 - 2 * i);      // exact in fp32
  const float2* ps = pairs_s + b * Dn;
  const float4* dp = desc + b * 128;

  float gm[32];
  float m = -3.4e38f;
#pragma unroll 8
  for (int q = 0; q < 32; ++q) {
    float4 d = dp[q * 4 + w];
    float t0 = fmaf(sc, d.x, d.y);         // T at group's min-x element
    float t1 = fmaf(sc, d.z, d.w);         // T at group's max-x element
    float g = fmaxf(t0, t1);
    gm[q] = g;
    m = fmaxf(m, g);
  }
  redM[w][lane] = m;
  __syncthreads();
  float M = fmaxf(fmaxf(redM[0][lane], redM[1][lane]),
                  fmaxf(redM[2][lane], redM[3][lane]));
  float thresh = M - 32.f;

  float se = 0.f, sd = 0.f;
#pragma unroll 4
  for (int q = 0; q < 32; ++q) {
    if (__any(gm[q] > thresh)) {
      int base = (q * 4 + w) * 8;
#pragma unroll
      for (int u = 0; u < 8; ++u) {
        float2 v = ps[base + u];
        float e = exp2_fast(fmaf(sc, v.x, v.y - M));
        se += e;
        sd = fmaf(e, v.x, sd);
      }
    }
  }
  redE[w][lane] = se;
  redD[w][lane] = sd;
  __syncthreads();
  if (tid < 64) {
    float SE = (redE[0][lane] + redE[1][lane]) + (redE[2][lane] + redE[3][lane]);
    float SD = (redD[0][lane] + redD[1][lane]) + (redD[2][lane] + redD[3][lane]);
    xs_out[b * Dn + rc * 64 + lane] = SD / SE * LN2;
  }
}

// ---------------------------------------------------------------------------
// K3/K4: h = leaky(in @ W^T + bias).  Block = 8 batches x 8 cols; thread
// tile = 1 batch x 4 cols x K/16.  grid = 1024 blocks.  TAIL fuses layer 3.
// ---------------------------------------------------------------------------
template <bool TAIL>
__global__ __launch_bounds__(256) void layer_kernel(
    const float* __restrict__ in, const float* __restrict__ W,
    const float* __restrict__ bias, float* __restrict__ out,
    const float* __restrict__ W3, const float* __restrict__ b3,
    float* __restrict__ out2) {
  __shared__ float s[8][Dn + 4];
  __shared__ float red[8][8][16];          // [bl][nl][kc]
  __shared__ float r2[8][8][2];
  int bc = blockIdx.x >> 7;                // batch chunk 0..7
  int nc = blockIdx.x & 127;               // col chunk 0..127
  int tid = threadIdx.x;
  const float* src = in + bc * 8 * Dn;
#pragma unroll
  for (int u = 0; u < 8; ++u) {
    int idx = (u * 256 + tid) << 2;
    *(float4*)&s[idx >> 10][idx & 1023] = *(const float4*)(src + idx);
  }
  __syncthreads();

  int bl = tid & 7;                        // local batch
  int nq = (tid >> 3) & 1;                 // col quad 0..1
  int kc = tid >> 4;                       // k chunk 0..15 (64 elems)
  int n0 = nc * 8 + nq * 4;
  const float* a  = &s[bl][kc * 64];
  const float* w0 = W + (size_t)(n0 + 0) * Dn + kc * 64;
  const float* w1 = W + (size_t)(n0 + 1) * Dn + kc * 64;
  const float* w2 = W + (size_t)(n0 + 2) * Dn + kc * 64;
  const float* w3 = W + (size_t)(n0 + 3) * Dn + kc * 64;
  float a0 = 0.f, a1 = 0.f, a2 = 0.f, a3 = 0.f;
#pragma unroll 4
  for (int kq = 0; kq < 16; ++kq) {
    float4 av = *(const float4*)(a + kq * 4);
    float4 b0 = *(const float4*)(w0 + kq * 4);
    float4 b1 = *(const float4*)(w1 + kq * 4);
    float4 b2 = *(const float4*)(w2 + kq * 4);
    float4 b3v = *(const float4*)(w3 + kq * 4);
    a0 = fmaf(av.x, b0.x, fmaf(av.y, b0.y, fmaf(av.z, b0.z, fmaf(av.w, b0.w, a0))));
    a1 = fmaf(av.x, b1.x, fmaf(av.y, b1.y, fmaf(av.z, b1.z, fmaf(av.w, b1.w, a1))));
    a2 = fmaf(av.x, b2.x, fmaf(av.y, b2.y, fmaf(av.z, b2.z, fmaf(av.w, b2.w, a2))));
    a3 = fmaf(av.x, b3v.x, fmaf(av.y, b3v.y, fmaf(av.z, b3v.z, fmaf(av.w, b3v.w, a3))));
  }
  red[bl][nq * 4 + 0][kc] = a0;
  red[bl][nq * 4 + 1][kc] = a1;
  red[bl][nq * 4 + 2][kc] = a2;
  red[bl][nq * 4 + 3][kc] = a3;
  __syncthreads();

  if (!TAIL) {
    if (tid < 64) {
      int bl2 = tid >> 3, nl2 = tid & 7;
      int n2 = nc * 8 + nl2;
      float hs = 0.f;
#pragma unroll
      for (int q = 0; q < 16; ++q) hs += red[bl2][nl2][q];
      float h = hs + bias[n2];
      h = h >= 0.f ? h : 0.01f * h;
      out[(bc * 8 + bl2) * Dn + n2] = h;
    }
  } else {
    if (tid < 64) {
      int bl2 = tid >> 3, nl2 = tid & 7;
      int n2 = nc * 8 + nl2;
      float hs = 0.f;
#pragma unroll
      for (int q = 0; q < 16; ++q) hs += red[bl2][nl2][q];
      float h = hs + bias[n2];
      h = h >= 0.f ? h : 0.01f * h;
      r2[bl2][nl2][0] = h * W3[n2];
      r2[bl2][nl2][1] = h * W3[Dn + n2];
    }
    __syncthreads();
    if (tid < 16) {
      int bl2 = tid >> 1, o = tid & 1;
      float t = 0.f;
#pragma unroll
      for (int q = 0; q < 8; ++q) t += r2[bl2][q][o];
      if (nc == 0) t += b3[o];
      atomicAdd(out2 + (bc * 8 + bl2) * 2 + o, t);
    }
  }
}

extern "C" void kernel_launch(void* const* d_in, const int* in_sizes, int n_in,
                              void* d_out, int out_size, void* d_ws, size_t ws_size,
                              hipStream_t stream) {
  const float* x  = (const float*)d_in[0];
  const float* W1 = (const float*)d_in[1];
  const float* b1 = (const float*)d_in[2];
  const float* W2 = (const float*)d_in[3];
  const float* b2 = (const float*)d_in[4];
  const float* W3 = (const float*)d_in[5];
  const float* b3 = (const float*)d_in[6];
  float* out = (float*)d_out;
  float* ws = (float*)d_ws;

  float2* pairs_s = (float2*)ws;                   // 64*1024 float2 = 512 KB
  float4* desc    = (float4*)(pairs_s + Bn * Dn);  // 64*128 float4 = 32 KB
  float*  xs      = (float*)(desc + Bn * 128);     // 256 KB
  float*  h1      = xs + Bn * Dn;                  // 256 KB

  k0_sort_bsum<<<Bn, 512, 0, stream>>>(x, pairs_s, desc, out);
  k2_softsort<<<Bn * 16, 256, 0, stream>>>(pairs_s, desc, xs);
  layer_kernel<false><<<1024, 256, 0, stream>>>(xs, W1, b1, h1,
                                                nullptr, nullptr, nullptr);
  layer_kernel<true><<<1024, 256, 0, stream>>>(h1, W2, b2, nullptr,
                                               W3, b3, out);
}

// Round 7
// 111.558 us; speedup vs baseline: 1.1202x; 1.0145x over previous
//
#include <hip/hip_runtime.h>
#include <math.h>

constexpr int Bn = 64;
constexpr int Dn = 1024;
constexpr float LOG2E = 1.4426950408889634f;
constexpr float LN2   = 0.6931471805599453f;

__device__ __forceinline__ float exp2_fast(float v) {
#if defined(__has_builtin)
#if __has_builtin(__builtin_amdgcn_exp2f)
  return __builtin_amdgcn_exp2f(v);
#else
  return exp2f(v);
#endif
#else
  return exp2f(v);
#endif
}

// ---------------------------------------------------------------------------
// K0: fused bucket-sort + analytic Bsum + pairs + group descriptors.
// TWO blocks (512 thr) per b: both duplicate the cheap count/scan/scatter;
// each handles half the positions for the serial local-sum + desc phases.
// Bsum = x*(Nlo-Nhi)+(Shi-Slo)+sum_{same bucket}|x-x_k| (exact).
// Descriptors per group of 8 sorted positions: exact (a,c) of the group's
// min-x/max-x elements (T concave -> endpoint bound).  Zeroes d_out.
// ---------------------------------------------------------------------------
__global__ __launch_bounds__(512) void k0_sort_bsum(
    const float* __restrict__ x, float2* __restrict__ pairs_s,
    float4* __restrict__ desc, float* __restrict__ out) {
  int b    = blockIdx.x >> 1;
  int half = blockIdx.x & 1;
  int tid = threadIdx.x;
  __shared__ float xs_[Dn];
  __shared__ float cs_[Dn];
  __shared__ int   bkt_[Dn];
  __shared__ int   cnt[64], base_[64], off_[64];
  __shared__ float Ssum[64], cN[64], cS[64];
  if (tid < 64) { cnt[tid] = 0; off_[tid] = 0; Ssum[tid] = 0.f; }
  __syncthreads();
  float2 v2 = *(const float2*)(x + b * Dn + tid * 2);
  float xv[2] = {v2.x, v2.y};
  int bk[2];
#pragma unroll
  for (int u = 0; u < 2; ++u) {
    float z = exp2_fast(-2.455532f * xv[u]);   // 2^{-1.702 x log2e} monotone
    float p = 1.f / (1.f + z);                 // ~Phi(x): near-uniform buckets
    int t = (int)(p * 64.f);
    bk[u] = t < 0 ? 0 : (t > 63 ? 63 : t);
    atomicAdd(&cnt[bk[u]], 1);
    atomicAdd(&Ssum[bk[u]], xv[u]);
  }
  __syncthreads();
  if (tid < 64) {                              // wave 0: dual prefix scan
    int c = cnt[tid]; int si = c;
    float fs = Ssum[tid]; float ss = fs;
#pragma unroll
    for (int d = 1; d < 64; d <<= 1) {
      int oi = __shfl_up(si, d, 64);
      float os = __shfl_up(ss, d, 64);
      if (tid >= d) { si += oi; ss += os; }
    }
    base_[tid] = si - c;                       // Nlo (exclusive)
    float Stot = __shfl(ss, 63, 64);
    float Slo = ss - fs;                       // exclusive sum prefix
    cN[tid] = (float)(2 * (si - c) + c - Dn);  // Nlo - Nhi
    cS[tid] = Stot - 2.f * Slo - fs;           // Shi - Slo
  }
  __syncthreads();
#pragma unroll
  for (int u = 0; u < 2; ++u) {
    int pos = base_[bk[u]] + atomicAdd(&off_[bk[u]], 1);
    xs_[pos] = xv[u];
    bkt_[pos] = bk[u];
  }
  __syncthreads();
  {
    int p = half * 512 + tid;                  // this block's half
    float xp = xs_[p];
    int q = bkt_[p];
    int lo = base_[q], hi = lo + cnt[q];
    float local = 0.f;
    for (int k = lo; k < hi; ++k) local += fabsf(xp - xs_[k]);
    float Bs = fmaf(xp, cN[q], cS[q]) + local;
    float c = -Bs * LOG2E;
    cs_[p] = c;
    pairs_s[b * Dn + p] = make_float2(xp * LOG2E, c);
  }
  __syncthreads();
  if (tid < 64) {                              // one group of 8 per thread
    int g = half * 64 + tid;
    int base = g * 8;
    float xlo = xs_[base], xhi = xlo;
    int ilo = base, ihi = base;
#pragma unroll
    for (int k = 1; k < 8; ++k) {
      float xx = xs_[base + k];
      if (xx < xlo) { xlo = xx; ilo = base + k; }
      if (xx > xhi) { xhi = xx; ihi = base + k; }
    }
    desc[b * 128 + g] =
        make_float4(xlo * LOG2E, cs_[ilo], xhi * LOG2E, cs_[ihi]);
  }
  if (b == 0 && half == 0 && tid < 128) out[tid] = 0.f;
}

// ---------------------------------------------------------------------------
// K2: xs[b,i] = sum_j softmax_j(sc_i*x_j - Bsum_j) * x_j  (exp2 domain).
// Lane = row; 4 waves own interleaved groups (g = 4q+w).  Group max via the
// concave endpoint bound (2 fma + max per group).  Vote-skip below M-32.
// grid = 64*16 = 1024 blocks of 256.
// ---------------------------------------------------------------------------
__global__ __launch_bounds__(256, 4) void k2_softsort(
    const float2* __restrict__ pairs_s, const float4* __restrict__ desc,
    float* __restrict__ xs_out) {
  __shared__ float redM[4][64], redE[4][64], redD[4][64];
  int b  = blockIdx.x >> 4;
  int rc = blockIdx.x & 15;
  int tid = threadIdx.x;
  int w = tid >> 6, lane = tid & 63;
  int i = rc * 64 + lane;
  float sc = (float)(Dn - 1 - 2 * i);      // exact in fp32
  const float2* ps = pairs_s + b * Dn;
  const float4* dp = desc + b * 128;

  float gm[32];
  float m = -3.4e38f;
#pragma unroll 8
  for (int q = 0; q < 32; ++q) {
    float4 d = dp[q * 4 + w];
    float t0 = fmaf(sc, d.x, d.y);         // T at group's min-x element
    float t1 = fmaf(sc, d.z, d.w);         // T at group's max-x element
    float g = fmaxf(t0, t1);
    gm[q] = g;
    m = fmaxf(m, g);
  }
  redM[w][lane] = m;
  __syncthreads();
  float M = fmaxf(fmaxf(redM[0][lane], redM[1][lane]),
                  fmaxf(redM[2][lane], redM[3][lane]));
  float thresh = M - 32.f;

  float se = 0.f, sd = 0.f;
#pragma unroll 4
  for (int q = 0; q < 32; ++q) {
    if (__any(gm[q] > thresh)) {
      int base = (q * 4 + w) * 8;
#pragma unroll
      for (int u = 0; u < 8; ++u) {
        float2 v = ps[base + u];
        float e = exp2_fast(fmaf(sc, v.x, v.y - M));
        se += e;
        sd = fmaf(e, v.x, sd);
      }
    }
  }
  redE[w][lane] = se;
  redD[w][lane] = sd;
  __syncthreads();
  if (tid < 64) {
    float SE = (redE[0][lane] + redE[1][lane]) + (redE[2][lane] + redE[3][lane]);
    float SD = (redD[0][lane] + redD[1][lane]) + (redD[2][lane] + redD[3][lane]);
    xs_out[b * Dn + rc * 64 + lane] = SD / SE * LN2;
  }
}

// ---------------------------------------------------------------------------
// K3/K4: h = leaky(in @ W^T + bias).  Block = 8 batches x 8 cols; thread
// tile = 1 batch x 4 cols x K/16.  grid = 1024 blocks.
// XCD-aware swizzle: xcd = blk&7 owns a contiguous 16-chunk nc range
// (512 KB of W, resident in that XCD's 4 MiB L2 across its 8 bc-blocks)
// -> ~8x less L3 W traffic.  Heuristic only; correctness placement-free.
// TAIL fuses layer 3 into atomicAdds on d_out (zeroed by k0).
// ---------------------------------------------------------------------------
template <bool TAIL>
__global__ __launch_bounds__(256) void layer_kernel(
    const float* __restrict__ in, const float* __restrict__ W,
    const float* __restrict__ bias, float* __restrict__ out,
    const float* __restrict__ W3, const float* __restrict__ b3,
    float* __restrict__ out2) {
  __shared__ float s[8][Dn + 4];
  __shared__ float red[8][8][16];          // [bl][nl][kc]
  __shared__ float r2[8][8][2];
  int xcd = blockIdx.x & 7;
  int idx = blockIdx.x >> 3;               // 0..127
  int nc = xcd * 16 + (idx & 15);          // col chunk 0..127
  int bc = idx >> 4;                       // batch chunk 0..7
  int tid = threadIdx.x;
  const float* src = in + bc * 8 * Dn;
#pragma unroll
  for (int u = 0; u < 8; ++u) {
    int idx2 = (u * 256 + tid) << 2;
    *(float4*)&s[idx2 >> 10][idx2 & 1023] = *(const float4*)(src + idx2);
  }
  __syncthreads();

  int bl = tid & 7;                        // local batch
  int nq = (tid >> 3) & 1;                 // col quad 0..1
  int kc = tid >> 4;                       // k chunk 0..15 (64 elems)
  int n0 = nc * 8 + nq * 4;
  const float* a  = &s[bl][kc * 64];
  const float* w0 = W + (size_t)(n0 + 0) * Dn + kc * 64;
  const float* w1 = W + (size_t)(n0 + 1) * Dn + kc * 64;
  const float* w2 = W + (size_t)(n0 + 2) * Dn + kc * 64;
  const float* w3 = W + (size_t)(n0 + 3) * Dn + kc * 64;
  float a0 = 0.f, a1 = 0.f, a2 = 0.f, a3 = 0.f;
#pragma unroll 4
  for (int kq = 0; kq < 16; ++kq) {
    float4 av = *(const float4*)(a + kq * 4);
    float4 b0 = *(const float4*)(w0 + kq * 4);
    float4 b1 = *(const float4*)(w1 + kq * 4);
    float4 b2 = *(const float4*)(w2 + kq * 4);
    float4 b3v = *(const float4*)(w3 + kq * 4);
    a0 = fmaf(av.x, b0.x, fmaf(av.y, b0.y, fmaf(av.z, b0.z, fmaf(av.w, b0.w, a0))));
    a1 = fmaf(av.x, b1.x, fmaf(av.y, b1.y, fmaf(av.z, b1.z, fmaf(av.w, b1.w, a1))));
    a2 = fmaf(av.x, b2.x, fmaf(av.y, b2.y, fmaf(av.z, b2.z, fmaf(av.w, b2.w, a2))));
    a3 = fmaf(av.x, b3v.x, fmaf(av.y, b3v.y, fmaf(av.z, b3v.z, fmaf(av.w, b3v.w, a3))));
  }
  red[bl][nq * 4 + 0][kc] = a0;
  red[bl][nq * 4 + 1][kc] = a1;
  red[bl][nq * 4 + 2][kc] = a2;
  red[bl][nq * 4 + 3][kc] = a3;
  __syncthreads();

  if (!TAIL) {
    if (tid < 64) {
      int bl2 = tid >> 3, nl2 = tid & 7;
      int n2 = nc * 8 + nl2;
      float hs = 0.f;
#pragma unroll
      for (int q = 0; q < 16; ++q) hs += red[bl2][nl2][q];
      float h = hs + bias[n2];
      h = h >= 0.f ? h : 0.01f * h;
      out[(bc * 8 + bl2) * Dn + n2] = h;
    }
  } else {
    if (tid < 64) {
      int bl2 = tid >> 3, nl2 = tid & 7;
      int n2 = nc * 8 + nl2;
      float hs = 0.f;
#pragma unroll
      for (int q = 0; q < 16; ++q) hs += red[bl2][nl2][q];
      float h = hs + bias[n2];
      h = h >= 0.f ? h : 0.01f * h;
      r2[bl2][nl2][0] = h * W3[n2];
      r2[bl2][nl2][1] = h * W3[Dn + n2];
    }
    __syncthreads();
    if (tid < 16) {
      int bl2 = tid >> 1, o = tid & 1;
      float t = 0.f;
#pragma unroll
      for (int q = 0; q < 8; ++q) t += r2[bl2][q][o];
      if (nc == 0) t += b3[o];
      atomicAdd(out2 + (bc * 8 + bl2) * 2 + o, t);
    }
  }
}

extern "C" void kernel_launch(void* const* d_in, const int* in_sizes, int n_in,
                              void* d_out, int out_size, void* d_ws, size_t ws_size,
                              hipStream_t stream) {
  const float* x  = (const float*)d_in[0];
  const float* W1 = (const float*)d_in[1];
  const float* b1 = (const float*)d_in[2];
  const float* W2 = (const float*)d_in[3];
  const float* b2 = (const float*)d_in[4];
  const float* W3 = (const float*)d_in[5];
  const float* b3 = (const float*)d_in[6];
  float* out = (float*)d_out;
  float* ws = (float*)d_ws;

  float2* pairs_s = (float2*)ws;                   // 64*1024 float2 = 512 KB
  float4* desc    = (float4*)(pairs_s + Bn * Dn);  // 64*128 float4 = 32 KB
  float*  xs      = (float*)(desc + Bn * 128);     // 256 KB
  float*  h1      = xs + Bn * Dn;                  // 256 KB

  k0_sort_bsum<<<Bn * 2, 512, 0, stream>>>(x, pairs_s, desc, out);
  k2_softsort<<<Bn * 16, 256, 0, stream>>>(pairs_s, desc, xs);
  layer_kernel<false><<<1024, 256, 0, stream>>>(xs, W1, b1, h1,
                                                nullptr, nullptr, nullptr);
  layer_kernel<true><<<1024, 256, 0, stream>>>(h1, W2, b2, nullptr,
                                               W3, b3, out);
}